// Round 3
// baseline (319.457 us; speedup 1.0000x reference)
//
#include <hip/hip_runtime.h>

#define TOK 4096
#define HID 1024
#define NEXP 8
#define CAP 512
#define WSZ 1048576  // HID*HID

typedef _Float16 f16;
typedef f16 f16x8 __attribute__((ext_vector_type(8)));
typedef f16 f16x4 __attribute__((ext_vector_type(4)));
typedef f16 f16x2 __attribute__((ext_vector_type(2)));
typedef float f32x4 __attribute__((ext_vector_type(4)));

typedef const __attribute__((address_space(1))) void gvoid;
typedef __attribute__((address_space(3))) void lvoid;

__device__ __forceinline__ void gld16(const void* g, void* l) {
  __builtin_amdgcn_global_load_lds((gvoid*)g, (lvoid*)l, 16, 0, 0);
}

// ---------------------------------------------------------------------------
// MFMA f16 GEMM: tile 128x128, BK=64, 256 thr = 4 waves (2x2), wave-tile 64x64
// (4x4 frags of 16x16x32). Double-buffered LDS, stage-ahead 2-phase pipeline.
// MODE 0: C[r][col] = v          (plain)
// MODE 1: A gathered via rowmap (-1 -> zero row TOK), C plain
// MODE 2: C[rowmap[r]][col] = v * gmax[rowmap[r]]  (skip r with rowmap=-1)
// LDS rows are 64 f16 (128B, 8 chunks of 16B) XOR-swizzled chunk^=(row&7),
// applied via pre-swizzled global source (global_load_lds writes linearly).
// ---------------------------------------------------------------------------
template<int MODE>
__global__ __launch_bounds__(256, 2) void gemm_h(
    const f16* __restrict__ A, const f16* __restrict__ Bt,
    const float* __restrict__ bias, f16* __restrict__ C,
    const int* __restrict__ rowmap, const float* __restrict__ gmax,
    int rowsPerExpert, long bStride, int biasStride)
{
  __shared__ f16 As[2][128 * 64];
  __shared__ f16 Bs[2][128 * 64];
  const int tid = threadIdx.x;
  const int w = tid >> 6, l = tid & 63;
  const int wr = w >> 1, wc = w & 1;
  const int bx = blockIdx.x, by = blockIdx.y;
  const int e = (by * 128) / rowsPerExpert;

  const int lr = l >> 3;                    // row within 8-row staging inst
  const int chunkSw = ((l & 7) ^ lr) * 8;   // pre-swizzled k-chunk (f16 elems)

  const f16* pa[4];
  #pragma unroll
  for (int i = 0; i < 4; ++i) {
    int r = by * 128 + w * 32 + i * 8 + lr;
    long tok = r;
    if (MODE == 1) { int t = rowmap[r]; tok = (t < 0) ? (long)TOK : (long)t; }
    pa[i] = A + tok * HID + chunkSw;
  }
  const f16* pb = Bt + (size_t)e * bStride
                + (size_t)(bx * 128 + w * 32 + lr) * HID + chunkSw;

  f32x4 acc[4][4];
  #pragma unroll
  for (int i = 0; i < 4; ++i)
    #pragma unroll
    for (int j = 0; j < 4; ++j) acc[i][j] = (f32x4){0.f, 0.f, 0.f, 0.f};

  const int g = l >> 4, c = l & 15, sa = c & 7;

  // prologue: stage k=0 into buf 0
  {
    f16* ab = &As[0][(w * 32) * 64];
    f16* bb = &Bs[0][(w * 32) * 64];
    #pragma unroll
    for (int i = 0; i < 4; ++i) gld16(pa[i], ab + i * 8 * 64);
    #pragma unroll
    for (int i = 0; i < 4; ++i) gld16(pb + (size_t)(i * 8) * HID, bb + i * 8 * 64);
  }
  __syncthreads();

  for (int t = 0; t < 16; ++t) {
    const int cur = t & 1;
    if (t < 15) {              // stage next K-tile first (overlaps compute)
      const int k0 = (t + 1) * 64;
      f16* ab = &As[cur ^ 1][(w * 32) * 64];
      f16* bb = &Bs[cur ^ 1][(w * 32) * 64];
      #pragma unroll
      for (int i = 0; i < 4; ++i) gld16(pa[i] + k0, ab + i * 8 * 64);
      #pragma unroll
      for (int i = 0; i < 4; ++i) gld16(pb + (size_t)(i * 8) * HID + k0, bb + i * 8 * 64);
    }
    #pragma unroll
    for (int h = 0; h < 2; ++h) {
      const int q = ((h * 4 + g) ^ sa) * 8;
      f16x8 af[4], bf[4];
      #pragma unroll
      for (int mi = 0; mi < 4; ++mi)
        af[mi] = *(const f16x8*)&As[cur][(wr * 64 + mi * 16 + c) * 64 + q];
      #pragma unroll
      for (int ni = 0; ni < 4; ++ni)
        bf[ni] = *(const f16x8*)&Bs[cur][(wc * 64 + ni * 16 + c) * 64 + q];
      #pragma unroll
      for (int mi = 0; mi < 4; ++mi)
        #pragma unroll
        for (int ni = 0; ni < 4; ++ni)
          acc[mi][ni] = __builtin_amdgcn_mfma_f32_16x16x32_f16(
              af[mi], bf[ni], acc[mi][ni], 0, 0, 0);
    }
    __syncthreads();   // drains vmcnt (staging) + syncs buffer swap
  }

  // epilogue: D col = lane&15, row = (lane>>4)*4 + reg
  int tk[4][4];
  float gv[4][4];
  if (MODE == 2) {
    #pragma unroll
    for (int mi = 0; mi < 4; ++mi)
      #pragma unroll
      for (int rr = 0; rr < 4; ++rr) {
        int r = by * 128 + wr * 64 + mi * 16 + g * 4 + rr;
        int t = rowmap[r];
        tk[mi][rr] = t;
        gv[mi][rr] = (t >= 0) ? gmax[t] : 0.f;
      }
  }
  #pragma unroll
  for (int ni = 0; ni < 4; ++ni) {
    const int col = bx * 128 + wc * 64 + ni * 16 + c;
    const float bv = bias[(size_t)e * biasStride + col];
    #pragma unroll
    for (int mi = 0; mi < 4; ++mi) {
      #pragma unroll
      for (int rr = 0; rr < 4; ++rr) {
        const float v = acc[mi][ni][rr] + bv;
        if (MODE == 2) {
          if (tk[mi][rr] >= 0)
            C[(size_t)tk[mi][rr] * HID + col] = (f16)(v * gv[mi][rr]);
        } else {
          const int row = by * 128 + wr * 64 + mi * 16 + g * 4 + rr;
          C[(size_t)row * HID + col] = (f16)v;
        }
      }
    }
  }
}

// ---------------------------------------------------------------------------
// Transpose-cast ALL weights: z in [0,35): 0..2 -> w1,w2,w3; 3..10 -> e1w1;
// 11..18 -> e1w2; 19..26 -> e2w1; 27..34 -> e2w2.  [k][n] f32 -> [n][k] f16.
// ---------------------------------------------------------------------------
__global__ __launch_bounds__(256) void tcast(
    const float* __restrict__ w1, const float* __restrict__ w2,
    const float* __restrict__ w3,
    const float* __restrict__ g1a, const float* __restrict__ g1b,
    const float* __restrict__ g2a, const float* __restrict__ g2b,
    f16* __restrict__ dst)
{
  __shared__ float t[64][65];
  const int z = blockIdx.z;
  const float* src; int zl = 0;
  if (z == 0) src = w1;
  else if (z == 1) src = w2;
  else if (z == 2) src = w3;
  else if (z < 11) { src = g1a; zl = z - 3; }
  else if (z < 19) { src = g1b; zl = z - 11; }
  else if (z < 27) { src = g2a; zl = z - 19; }
  else             { src = g2b; zl = z - 27; }
  src += (size_t)zl * WSZ;
  f16* d = dst + (size_t)z * WSZ;

  const int tid = threadIdx.x;
  const int kb = blockIdx.y * 64, nb = blockIdx.x * 64;
  const int r = tid >> 4, c4 = (tid & 15) * 4;
  #pragma unroll
  for (int p = 0; p < 4; ++p) {
    float4 v = *(const float4*)&src[(size_t)(kb + p * 16 + r) * HID + nb + c4];
    t[p * 16 + r][c4 + 0] = v.x;
    t[p * 16 + r][c4 + 1] = v.y;
    t[p * 16 + r][c4 + 2] = v.z;
    t[p * 16 + r][c4 + 3] = v.w;
  }
  __syncthreads();
  #pragma unroll
  for (int p = 0; p < 4; ++p) {
    int n = p * 16 + r;
    f16x4 o = {(f16)t[c4 + 0][n], (f16)t[c4 + 1][n],
               (f16)t[c4 + 2][n], (f16)t[c4 + 3][n]};
    *(f16x4*)&d[(size_t)(nb + n) * HID + kb + c4] = o;
  }
}

// ---------------------------------------------------------------------------
__global__ void castx(const float* __restrict__ src, f16* __restrict__ dst) {
  int i = blockIdx.x * 256 + threadIdx.x;
  float4 v = *(const float4*)&src[(size_t)i * 4];
  f16x4 o = {(f16)v.x, (f16)v.y, (f16)v.z, (f16)v.w};
  *(f16x4*)&dst[(size_t)i * 4] = o;
}

// zero C1, C2 (4096x1024 each) + the two gather pad rows
__global__ void zinit(f16* c1, f16* c2, f16* p1, f16* p2) {
  const size_t i = (size_t)blockIdx.x * 256 + threadIdx.x;  // 524288 threads
  const f16x8 z = {0, 0, 0, 0, 0, 0, 0, 0};
  ((f16x8*)c1)[i] = z;
  ((f16x8*)c2)[i] = z;
  if (i < 128) { ((f16x8*)p1)[i] = z; ((f16x8*)p2)[i] = z; }
}

// ---------------------------------------------------------------------------
// Gating from f16 activations: 8 tokens/block, 32 lanes/token, f32 accum.
// ---------------------------------------------------------------------------
__global__ __launch_bounds__(256) void gate_kernel(
    const f16* __restrict__ act, const float* __restrict__ wg,
    int* __restrict__ idx, float* __restrict__ gmax)
{
  const int tid = threadIdx.x;
  const int tok = blockIdx.x * 8 + (tid >> 5);
  const int sl = tid & 31;
  const f16* row = act + (size_t)tok * HID + sl * 32;
  float xv[32];
  #pragma unroll
  for (int v = 0; v < 4; ++v) {
    f16x8 hv = *(const f16x8*)(row + v * 8);
    #pragma unroll
    for (int j = 0; j < 8; ++j) xv[v * 8 + j] = (float)hv[j];
  }
  float p[NEXP];
  #pragma unroll
  for (int e = 0; e < NEXP; ++e) p[e] = 0.f;
  const float* wr_ = wg + (size_t)(sl * 32) * NEXP;
  #pragma unroll
  for (int j = 0; j < 32; ++j) {
    #pragma unroll
    for (int e = 0; e < NEXP; ++e) p[e] += xv[j] * wr_[j * NEXP + e];
  }
  #pragma unroll
  for (int m = 1; m < 32; m <<= 1) {
    #pragma unroll
    for (int e = 0; e < NEXP; ++e) p[e] += __shfl_xor(p[e], m, 64);
  }
  if (sl == 0) {
    float mx = p[0]; int am = 0;
    #pragma unroll
    for (int e = 1; e < NEXP; ++e)
      if (p[e] > mx) { mx = p[e]; am = e; }
    float s = 0.f;
    #pragma unroll
    for (int e = 0; e < NEXP; ++e) s += expf(p[e] - mx);
    idx[tok] = am;
    gmax[tok] = 1.f / s;
  }
}

// ---------------------------------------------------------------------------
// Capacity scan (cumsum-of-one_hot semantics): wave e owns expert e.
// ---------------------------------------------------------------------------
__global__ __launch_bounds__(512) void scan_kernel(
    const int* __restrict__ idx, int* __restrict__ rowmap)
{
  __shared__ int sidx[TOK];
  const int tid = threadIdx.x;
  for (int i = tid; i < TOK; i += 512) sidx[i] = idx[i];
  for (int i = tid; i < NEXP * CAP; i += 512) rowmap[i] = -1;
  __syncthreads();
  const int wave = tid >> 6, lane = tid & 63;
  int running = 0;
  for (int ch = 0; ch < TOK / 64; ++ch) {
    int t = ch * 64 + lane;
    bool flag = (sidx[t] == wave);
    unsigned long long m = __ballot(flag);
    int pos = running + __popcll(m & ((1ull << lane) - 1ull));
    if (flag && pos < CAP) rowmap[wave * CAP + pos] = t;
    running += __popcll(m);
  }
}

// ---------------------------------------------------------------------------
// sent[b][h] = mean_s (a + c), f16 inputs, f32 accum.  grid (2,8), 256 thr.
// ---------------------------------------------------------------------------
__global__ __launch_bounds__(256) void mean_kernel(
    const f16* __restrict__ a, const f16* __restrict__ c,
    float* __restrict__ sent)
{
  const int h2 = blockIdx.x * 256 + threadIdx.x;  // f16x2 column, 0..511
  const int b = blockIdx.y;
  const f16x2* pa = (const f16x2*)(a + (size_t)b * 512 * HID) + h2;
  const f16x2* pc = (const f16x2*)(c + (size_t)b * 512 * HID) + h2;
  float a0 = 0.f, a1 = 0.f;
  for (int s = 0; s < 512; ++s) {
    f16x2 va = pa[(size_t)s * 512];
    f16x2 vc = pc[(size_t)s * 512];
    a0 += (float)va[0] + (float)vc[0];
    a1 += (float)va[1] + (float)vc[1];
  }
  sent[b * HID + h2 * 2]     = a0 * (1.f / 512.f);
  sent[b * HID + h2 * 2 + 1] = a1 * (1.f / 512.f);
}

__global__ __launch_bounds__(1024) void loss_kernel(
    const float* __restrict__ sent, const int* __restrict__ y,
    float* __restrict__ out)
{
  __shared__ float red[1024];
  float loss = 0.0f;
  for (int b = 0; b < 8; ++b) {
    float v = sent[b * HID + threadIdx.x];
    red[threadIdx.x] = v;
    __syncthreads();
    for (int s = 512; s > 0; s >>= 1) {
      if (threadIdx.x < s)
        red[threadIdx.x] = fmaxf(red[threadIdx.x], red[threadIdx.x + s]);
      __syncthreads();
    }
    float m = red[0];
    __syncthreads();
    red[threadIdx.x] = expf(v - m);
    __syncthreads();
    for (int s = 512; s > 0; s >>= 1) {
      if (threadIdx.x < s) red[threadIdx.x] += red[threadIdx.x + s];
      __syncthreads();
    }
    if (threadIdx.x == 0) {
      float lse = m + logf(red[0]);
      loss += -(sent[b * HID + y[b]] - lse);
    }
    __syncthreads();
  }
  if (threadIdx.x == 0) out[0] = loss * (1.0f / 8.0f);
}

// ---------------------------------------------------------------------------
extern "C" void kernel_launch(void* const* d_in, const int* in_sizes, int n_in,
                              void* d_out, int out_size, void* d_ws, size_t ws_size,
                              hipStream_t stream)
{
  const float* x    = (const float*)d_in[0];
  const int*   y    = (const int*)d_in[1];
  const float* w1   = (const float*)d_in[2];
  const float* b1   = (const float*)d_in[3];
  const float* w2   = (const float*)d_in[4];
  const float* b2   = (const float*)d_in[5];
  const float* w3   = (const float*)d_in[6];
  const float* b3   = (const float*)d_in[7];
  const float* wg1  = (const float*)d_in[8];
  const float* e1w1 = (const float*)d_in[9];
  const float* e1b1 = (const float*)d_in[10];
  const float* e1w2 = (const float*)d_in[11];
  const float* e1b2 = (const float*)d_in[12];
  const float* wg2  = (const float*)d_in[13];
  const float* e2w1 = (const float*)d_in[14];
  const float* e2b1 = (const float*)d_in[15];
  const float* e2w2 = (const float*)d_in[16];
  const float* e2b2 = (const float*)d_in[17];

  // workspace (~134 MB of the ~256 MB available)
  f16* WT = (f16*)d_ws;                          // 35 x [1024][1024] f16
  f16* X0 = WT + (size_t)35 * WSZ;               // [4096][1024]
  f16* H  = X0 + (size_t)TOK * HID;              // [4097][1024] (pad row)
  f16* EA = H + (size_t)(TOK + 1) * HID;         // [4096][1024] expert hidden
  f16* C1 = EA + (size_t)TOK * HID;              // [4096][1024] combine1 out
  f16* M1 = C1 + (size_t)TOK * HID;              // [4097][1024] (pad row)
  f16* C2 = M1 + (size_t)(TOK + 1) * HID;        // [4096][1024] combine2 out
  f16* O  = C2 + (size_t)TOK * HID;              // [4096][1024] final proj
  float* gmax  = (float*)(O + (size_t)TOK * HID);
  int* idx     = (int*)(gmax + TOK);
  int* rowmap  = idx + TOK;
  float* sent  = (float*)(rowmap + TOK);

  dim3 gg(HID / 128, TOK / 128);                 // (8, 32)

  zinit<<<2048, 256, 0, stream>>>(C1, C2, H + (size_t)TOK * HID, M1 + (size_t)TOK * HID);
  castx<<<4096, 256, 0, stream>>>(x, X0);
  tcast<<<dim3(16, 16, 35), 256, 0, stream>>>(w1, w2, w3, e1w1, e1w2, e2w1, e2w2, WT);

  // hidden = x @ w1 + b1
  gemm_h<0><<<gg, 256, 0, stream>>>(X0, WT, b1, H, nullptr, nullptr, TOK, 0, 0);

  // ---- MoE layer 1 ----
  gate_kernel<<<512, 256, 0, stream>>>(H, wg1, idx, gmax);
  scan_kernel<<<1, 512, 0, stream>>>(idx, rowmap);
  gemm_h<1><<<gg, 256, 0, stream>>>(H,  WT + (size_t)3 * WSZ,  e1b1, EA, rowmap, nullptr, CAP, WSZ, HID);
  gemm_h<2><<<gg, 256, 0, stream>>>(EA, WT + (size_t)11 * WSZ, e1b2, C1, rowmap, gmax,    CAP, WSZ, HID);

  // out = moe1 @ w2 + b2
  gemm_h<0><<<gg, 256, 0, stream>>>(C1, WT + (size_t)1 * WSZ, b2, M1, nullptr, nullptr, TOK, 0, 0);

  // ---- MoE layer 2 ----
  gate_kernel<<<512, 256, 0, stream>>>(M1, wg2, idx, gmax);
  scan_kernel<<<1, 512, 0, stream>>>(idx, rowmap);
  gemm_h<1><<<gg, 256, 0, stream>>>(M1, WT + (size_t)19 * WSZ, e2b1, EA, rowmap, nullptr, CAP, WSZ, HID);
  gemm_h<2><<<gg, 256, 0, stream>>>(EA, WT + (size_t)27 * WSZ, e2b2, C2, rowmap, gmax,    CAP, WSZ, HID);

  // out = moe2 @ w3 + b3
  gemm_h<0><<<gg, 256, 0, stream>>>(C2, WT + (size_t)2 * WSZ, b3, O, nullptr, nullptr, TOK, 0, 0);

  // final reduction
  mean_kernel<<<dim3(2, 8), 256, 0, stream>>>(H, O, sent);
  loss_kernel<<<1, 1024, 0, stream>>>(sent, y, (float*)d_out);
}

// Round 4
// 308.534 us; speedup vs baseline: 1.0354x; 1.0354x over previous
//
#include <hip/hip_runtime.h>

#define TOK 4096
#define HID 1024
#define NEXP 8
#define CAP 512
#define WSZ 1048576  // HID*HID

typedef _Float16 f16;
typedef f16 f16x8 __attribute__((ext_vector_type(8)));
typedef f16 f16x4 __attribute__((ext_vector_type(4)));
typedef f16 f16x2 __attribute__((ext_vector_type(2)));
typedef float f32x4 __attribute__((ext_vector_type(4)));

typedef const __attribute__((address_space(1))) void gvoid;
typedef __attribute__((address_space(3))) void lvoid;

__device__ __forceinline__ void gld16(const void* g, void* l) {
  __builtin_amdgcn_global_load_lds((gvoid*)g, (lvoid*)l, 16, 0, 0);
}

// ---------------------------------------------------------------------------
// MFMA f16 GEMM: tile 64x128, BK=64, 4 waves, wave-tile 64x32 (4x2 frags).
// Grid 512 blocks -> 2 blocks/CU (LDS 48KB, LB(256,2)).
// Double-buffered LDS, stage-ahead 2-phase pipeline (T3 minimum).
// MODE 0: C[r][col] = v
// MODE 1: A gathered via rowmap (-1 -> zero row TOK), C plain
// MODE 2: C[rowmap[r]][col] = v * gmax[rowmap[r]]  (skip r with rowmap=-1)
// LDS rows are 64 f16 (8 chunks of 16B), XOR-swizzled chunk^=(row&7) via
// pre-swizzled global source (global_load_lds writes linearly).
// ---------------------------------------------------------------------------
template<int MODE>
__global__ __launch_bounds__(256, 2) void gemm_h(
    const f16* __restrict__ A, const f16* __restrict__ Bt,
    const float* __restrict__ bias, f16* __restrict__ C,
    const int* __restrict__ rowmap, const float* __restrict__ gmax,
    int rowsPerExpert, long bStride, int biasStride)
{
  __shared__ f16 As[2][64 * 64];
  __shared__ f16 Bs[2][128 * 64];
  const int tid = threadIdx.x;
  const int w = tid >> 6, l = tid & 63;
  const int bx = blockIdx.x, by = blockIdx.y;
  const int e = (by * 64) / rowsPerExpert;

  const int lr = l >> 3;                    // row within 8-row staging inst
  const int chunkSw = ((l & 7) ^ lr) * 8;   // pre-swizzled k-chunk (f16 elems)

  // A staging: wave w owns rows w*16 .. w*16+15 (2 insts)
  const f16* pa[2];
  #pragma unroll
  for (int i = 0; i < 2; ++i) {
    int r = by * 64 + w * 16 + i * 8 + lr;
    long tok = r;
    if (MODE == 1) { int t = rowmap[r]; tok = (t < 0) ? (long)TOK : (long)t; }
    pa[i] = A + tok * HID + chunkSw;
  }
  // B staging: wave w owns n-rows w*32 .. w*32+31 (4 insts)
  const f16* pb = Bt + (size_t)e * bStride
                + (size_t)(bx * 128 + w * 32 + lr) * HID + chunkSw;

  f32x4 acc[4][2];
  #pragma unroll
  for (int i = 0; i < 4; ++i)
    #pragma unroll
    for (int j = 0; j < 2; ++j) acc[i][j] = (f32x4){0.f, 0.f, 0.f, 0.f};

  const int g = l >> 4, c = l & 15, sa = c & 7;

  // prologue: stage k=0 into buf 0
  {
    f16* ab = &As[0][(w * 16) * 64];
    f16* bb = &Bs[0][(w * 32) * 64];
    #pragma unroll
    for (int i = 0; i < 2; ++i) gld16(pa[i], ab + i * 8 * 64);
    #pragma unroll
    for (int i = 0; i < 4; ++i) gld16(pb + (size_t)(i * 8) * HID, bb + i * 8 * 64);
  }
  __syncthreads();

  for (int t = 0; t < 16; ++t) {
    const int cur = t & 1;
    if (t < 15) {              // stage next K-tile (overlaps with compute below)
      const int k0 = (t + 1) * 64;
      f16* ab = &As[cur ^ 1][(w * 16) * 64];
      f16* bb = &Bs[cur ^ 1][(w * 32) * 64];
      #pragma unroll
      for (int i = 0; i < 2; ++i) gld16(pa[i] + k0, ab + i * 8 * 64);
      #pragma unroll
      for (int i = 0; i < 4; ++i) gld16(pb + (size_t)(i * 8) * HID + k0, bb + i * 8 * 64);
    }
    #pragma unroll
    for (int h = 0; h < 2; ++h) {
      const int q = ((h * 4 + g) ^ sa) * 8;
      f16x8 af[4], bf[2];
      #pragma unroll
      for (int mi = 0; mi < 4; ++mi)
        af[mi] = *(const f16x8*)&As[cur][(mi * 16 + c) * 64 + q];
      #pragma unroll
      for (int ni = 0; ni < 2; ++ni)
        bf[ni] = *(const f16x8*)&Bs[cur][(w * 32 + ni * 16 + c) * 64 + q];
      #pragma unroll
      for (int mi = 0; mi < 4; ++mi)
        #pragma unroll
        for (int ni = 0; ni < 2; ++ni)
          acc[mi][ni] = __builtin_amdgcn_mfma_f32_16x16x32_f16(
              af[mi], bf[ni], acc[mi][ni], 0, 0, 0);
    }
    __syncthreads();   // drains vmcnt (staging) + buffer-swap sync
  }

  // epilogue: D col = lane&15, row = (lane>>4)*4 + reg
  int tk[4][4];
  float gv[4][4];
  if (MODE == 2) {
    #pragma unroll
    for (int mi = 0; mi < 4; ++mi)
      #pragma unroll
      for (int rr = 0; rr < 4; ++rr) {
        int r = by * 64 + mi * 16 + g * 4 + rr;
        int t = rowmap[r];
        tk[mi][rr] = t;
        gv[mi][rr] = (t >= 0) ? gmax[t] : 0.f;
      }
  }
  #pragma unroll
  for (int ni = 0; ni < 2; ++ni) {
    const int col = bx * 128 + w * 32 + ni * 16 + c;
    const float bv = bias[(size_t)e * biasStride + col];
    #pragma unroll
    for (int mi = 0; mi < 4; ++mi) {
      #pragma unroll
      for (int rr = 0; rr < 4; ++rr) {
        const float v = acc[mi][ni][rr] + bv;
        if (MODE == 2) {
          if (tk[mi][rr] >= 0)
            C[(size_t)tk[mi][rr] * HID + col] = (f16)(v * gv[mi][rr]);
        } else {
          const int row = by * 64 + mi * 16 + g * 4 + rr;
          C[(size_t)row * HID + col] = (f16)v;
        }
      }
    }
  }
}

// ---------------------------------------------------------------------------
// Transpose-cast ALL weights, conflict-free: z in [0,35): 0..2 -> w1,w2,w3;
// 3..10 -> e1w1; 11..18 -> e1w2; 19..26 -> e2w1; 27..34 -> e2w2.
// 64k x 64n tiles; LDS [64][65] f32 (2-way banks both phases = free);
// float4 coalesced reads, f16x8 writes in 128B segments.
// ---------------------------------------------------------------------------
__global__ __launch_bounds__(256) void tcast(
    const float* __restrict__ w1, const float* __restrict__ w2,
    const float* __restrict__ w3,
    const float* __restrict__ g1a, const float* __restrict__ g1b,
    const float* __restrict__ g2a, const float* __restrict__ g2b,
    f16* __restrict__ dst)
{
  __shared__ float t[64][65];
  const int z = blockIdx.z;
  const float* src; int zl = 0;
  if (z == 0) src = w1;
  else if (z == 1) src = w2;
  else if (z == 2) src = w3;
  else if (z < 11) { src = g1a; zl = z - 3; }
  else if (z < 19) { src = g1b; zl = z - 11; }
  else if (z < 27) { src = g2a; zl = z - 19; }
  else             { src = g2b; zl = z - 27; }
  src += (size_t)zl * WSZ;
  f16* d = dst + (size_t)z * WSZ;

  const int tid = threadIdx.x;
  const int kb = blockIdx.y * 64, nb = blockIdx.x * 64;
  const int r = tid >> 4, c4 = (tid & 15) * 4;
  #pragma unroll
  for (int p = 0; p < 4; ++p) {
    float4 v = *(const float4*)&src[(size_t)(kb + p * 16 + r) * HID + nb + c4];
    t[p * 16 + r][c4 + 0] = v.x;
    t[p * 16 + r][c4 + 1] = v.y;
    t[p * 16 + r][c4 + 2] = v.z;
    t[p * 16 + r][c4 + 3] = v.w;
  }
  __syncthreads();
  // read-out: piece p -> n = p>>3, kc = p&7; lane reads column n, rows kc*8..+7
  #pragma unroll
  for (int half = 0; half < 2; ++half) {
    const int p = half * 256 + tid;
    const int n = p >> 3, kc = p & 7;
    f16x8 o;
    #pragma unroll
    for (int j = 0; j < 8; ++j) o[j] = (f16)t[kc * 8 + j][n];
    *(f16x8*)&d[(size_t)(nb + n) * HID + kb + kc * 8] = o;
  }
}

// ---------------------------------------------------------------------------
__global__ void castx(const float* __restrict__ src, f16* __restrict__ dst) {
  int i = blockIdx.x * 256 + threadIdx.x;
  float4 v = *(const float4*)&src[(size_t)i * 4];
  f16x4 o = {(f16)v.x, (f16)v.y, (f16)v.z, (f16)v.w};
  *(f16x4*)&dst[(size_t)i * 4] = o;
}

// zero C1, C2 (4096x1024 each) + the two gather pad rows
__global__ void zinit(f16* c1, f16* c2, f16* p1, f16* p2) {
  const size_t i = (size_t)blockIdx.x * 256 + threadIdx.x;  // 524288 threads
  const f16x8 z = {0, 0, 0, 0, 0, 0, 0, 0};
  ((f16x8*)c1)[i] = z;
  ((f16x8*)c2)[i] = z;
  if (i < 128) { ((f16x8*)p1)[i] = z; ((f16x8*)p2)[i] = z; }
}

// ---------------------------------------------------------------------------
// Gating from f16 activations: 8 tokens/block, 32 lanes/token, f32 accum.
// ---------------------------------------------------------------------------
__global__ __launch_bounds__(256) void gate_kernel(
    const f16* __restrict__ act, const float* __restrict__ wg,
    int* __restrict__ idx, float* __restrict__ gmax)
{
  const int tid = threadIdx.x;
  const int tok = blockIdx.x * 8 + (tid >> 5);
  const int sl = tid & 31;
  const f16* row = act + (size_t)tok * HID + sl * 32;
  float xv[32];
  #pragma unroll
  for (int v = 0; v < 4; ++v) {
    f16x8 hv = *(const f16x8*)(row + v * 8);
    #pragma unroll
    for (int j = 0; j < 8; ++j) xv[v * 8 + j] = (float)hv[j];
  }
  float p[NEXP];
  #pragma unroll
  for (int e = 0; e < NEXP; ++e) p[e] = 0.f;
  const float* wr_ = wg + (size_t)(sl * 32) * NEXP;
  #pragma unroll
  for (int j = 0; j < 32; ++j) {
    #pragma unroll
    for (int e = 0; e < NEXP; ++e) p[e] += xv[j] * wr_[j * NEXP + e];
  }
  #pragma unroll
  for (int m = 1; m < 32; m <<= 1) {
    #pragma unroll
    for (int e = 0; e < NEXP; ++e) p[e] += __shfl_xor(p[e], m, 64);
  }
  if (sl == 0) {
    float mx = p[0]; int am = 0;
    #pragma unroll
    for (int e = 1; e < NEXP; ++e)
      if (p[e] > mx) { mx = p[e]; am = e; }
    float s = 0.f;
    #pragma unroll
    for (int e = 0; e < NEXP; ++e) s += expf(p[e] - mx);
    idx[tok] = am;
    gmax[tok] = 1.f / s;
  }
}

// ---------------------------------------------------------------------------
// Capacity scan (cumsum-of-one_hot semantics): wave e owns expert e.
// ---------------------------------------------------------------------------
__global__ __launch_bounds__(512) void scan_kernel(
    const int* __restrict__ idx, int* __restrict__ rowmap)
{
  __shared__ int sidx[TOK];
  const int tid = threadIdx.x;
  for (int i = tid; i < TOK; i += 512) sidx[i] = idx[i];
  for (int i = tid; i < NEXP * CAP; i += 512) rowmap[i] = -1;
  __syncthreads();
  const int wave = tid >> 6, lane = tid & 63;
  int running = 0;
  for (int ch = 0; ch < TOK / 64; ++ch) {
    int t = ch * 64 + lane;
    bool flag = (sidx[t] == wave);
    unsigned long long m = __ballot(flag);
    int pos = running + __popcll(m & ((1ull << lane) - 1ull));
    if (flag && pos < CAP) rowmap[wave * CAP + pos] = t;
    running += __popcll(m);
  }
}

// ---------------------------------------------------------------------------
// sent[b][h] = mean_s (a + c), f16 inputs, f32 accum.  grid (2,8), 256 thr.
// ---------------------------------------------------------------------------
__global__ __launch_bounds__(256) void mean_kernel(
    const f16* __restrict__ a, const f16* __restrict__ c,
    float* __restrict__ sent)
{
  const int h2 = blockIdx.x * 256 + threadIdx.x;  // f16x2 column, 0..511
  const int b = blockIdx.y;
  const f16x2* pa = (const f16x2*)(a + (size_t)b * 512 * HID) + h2;
  const f16x2* pc = (const f16x2*)(c + (size_t)b * 512 * HID) + h2;
  float a0 = 0.f, a1 = 0.f;
  for (int s = 0; s < 512; ++s) {
    f16x2 va = pa[(size_t)s * 512];
    f16x2 vc = pc[(size_t)s * 512];
    a0 += (float)va[0] + (float)vc[0];
    a1 += (float)va[1] + (float)vc[1];
  }
  sent[b * HID + h2 * 2]     = a0 * (1.f / 512.f);
  sent[b * HID + h2 * 2 + 1] = a1 * (1.f / 512.f);
}

__global__ __launch_bounds__(1024) void loss_kernel(
    const float* __restrict__ sent, const int* __restrict__ y,
    float* __restrict__ out)
{
  __shared__ float red[1024];
  float loss = 0.0f;
  for (int b = 0; b < 8; ++b) {
    float v = sent[b * HID + threadIdx.x];
    red[threadIdx.x] = v;
    __syncthreads();
    for (int s = 512; s > 0; s >>= 1) {
      if (threadIdx.x < s)
        red[threadIdx.x] = fmaxf(red[threadIdx.x], red[threadIdx.x + s]);
      __syncthreads();
    }
    float m = red[0];
    __syncthreads();
    red[threadIdx.x] = expf(v - m);
    __syncthreads();
    for (int s = 512; s > 0; s >>= 1) {
      if (threadIdx.x < s) red[threadIdx.x] += red[threadIdx.x + s];
      __syncthreads();
    }
    if (threadIdx.x == 0) {
      float lse = m + logf(red[0]);
      loss += -(sent[b * HID + y[b]] - lse);
    }
    __syncthreads();
  }
  if (threadIdx.x == 0) out[0] = loss * (1.0f / 8.0f);
}

// ---------------------------------------------------------------------------
extern "C" void kernel_launch(void* const* d_in, const int* in_sizes, int n_in,
                              void* d_out, int out_size, void* d_ws, size_t ws_size,
                              hipStream_t stream)
{
  const float* x    = (const float*)d_in[0];
  const int*   y    = (const int*)d_in[1];
  const float* w1   = (const float*)d_in[2];
  const float* b1   = (const float*)d_in[3];
  const float* w2   = (const float*)d_in[4];
  const float* b2   = (const float*)d_in[5];
  const float* w3   = (const float*)d_in[6];
  const float* b3   = (const float*)d_in[7];
  const float* wg1  = (const float*)d_in[8];
  const float* e1w1 = (const float*)d_in[9];
  const float* e1b1 = (const float*)d_in[10];
  const float* e1w2 = (const float*)d_in[11];
  const float* e1b2 = (const float*)d_in[12];
  const float* wg2  = (const float*)d_in[13];
  const float* e2w1 = (const float*)d_in[14];
  const float* e2b1 = (const float*)d_in[15];
  const float* e2w2 = (const float*)d_in[16];
  const float* e2b2 = (const float*)d_in[17];

  // workspace (~134 MB)
  f16* WT = (f16*)d_ws;                          // 35 x [1024][1024] f16
  f16* X0 = WT + (size_t)35 * WSZ;               // [4096][1024]
  f16* H  = X0 + (size_t)TOK * HID;              // [4097][1024] (pad row)
  f16* EA = H + (size_t)(TOK + 1) * HID;         // [4096][1024] expert hidden
  f16* C1 = EA + (size_t)TOK * HID;              // [4096][1024] combine1 out
  f16* M1 = C1 + (size_t)TOK * HID;              // [4097][1024] (pad row)
  f16* C2 = M1 + (size_t)(TOK + 1) * HID;        // [4096][1024] combine2 out
  f16* O  = C2 + (size_t)TOK * HID;              // [4096][1024] final proj
  float* gmax  = (float*)(O + (size_t)TOK * HID);
  int* idx     = (int*)(gmax + TOK);
  int* rowmap  = idx + TOK;
  float* sent  = (float*)(rowmap + TOK);

  dim3 gg(HID / 128, TOK / 64);                  // (8, 64) = 512 blocks

  zinit<<<2048, 256, 0, stream>>>(C1, C2, H + (size_t)TOK * HID, M1 + (size_t)TOK * HID);
  castx<<<4096, 256, 0, stream>>>(x, X0);
  tcast<<<dim3(16, 16, 35), 256, 0, stream>>>(w1, w2, w3, e1w1, e1w2, e2w1, e2w2, WT);

  // hidden = x @ w1 + b1
  gemm_h<0><<<gg, 256, 0, stream>>>(X0, WT, b1, H, nullptr, nullptr, TOK, 0, 0);

  // ---- MoE layer 1 ----
  gate_kernel<<<512, 256, 0, stream>>>(H, wg1, idx, gmax);
  scan_kernel<<<1, 512, 0, stream>>>(idx, rowmap);
  gemm_h<1><<<gg, 256, 0, stream>>>(H,  WT + (size_t)3 * WSZ,  e1b1, EA, rowmap, nullptr, CAP, WSZ, HID);
  gemm_h<2><<<gg, 256, 0, stream>>>(EA, WT + (size_t)11 * WSZ, e1b2, C1, rowmap, gmax,    CAP, WSZ, HID);

  // out = moe1 @ w2 + b2
  gemm_h<0><<<gg, 256, 0, stream>>>(C1, WT + (size_t)1 * WSZ, b2, M1, nullptr, nullptr, TOK, 0, 0);

  // ---- MoE layer 2 ----
  gate_kernel<<<512, 256, 0, stream>>>(M1, wg2, idx, gmax);
  scan_kernel<<<1, 512, 0, stream>>>(idx, rowmap);
  gemm_h<1><<<gg, 256, 0, stream>>>(M1, WT + (size_t)19 * WSZ, e2b1, EA, rowmap, nullptr, CAP, WSZ, HID);
  gemm_h<2><<<gg, 256, 0, stream>>>(EA, WT + (size_t)27 * WSZ, e2b2, C2, rowmap, gmax,    CAP, WSZ, HID);

  // out = moe2 @ w3 + b3
  gemm_h<0><<<gg, 256, 0, stream>>>(C2, WT + (size_t)2 * WSZ, b3, O, nullptr, nullptr, TOK, 0, 0);

  // final reduction
  mean_kernel<<<dim3(2, 8), 256, 0, stream>>>(H, O, sent);
  loss_kernel<<<1, 1024, 0, stream>>>(sent, y, (float*)d_out);
}

// Round 5
// 263.015 us; speedup vs baseline: 1.2146x; 1.1731x over previous
//
#include <hip/hip_runtime.h>

#define TOK 4096
#define HID 1024
#define NEXP 8
#define CAP 512
#define WSZ 1048576  // HID*HID

typedef _Float16 f16;
typedef f16 f16x8 __attribute__((ext_vector_type(8)));
typedef f16 f16x4 __attribute__((ext_vector_type(4)));
typedef f16 f16x2 __attribute__((ext_vector_type(2)));
typedef float f32x4 __attribute__((ext_vector_type(4)));

typedef const __attribute__((address_space(1))) void gvoid;
typedef __attribute__((address_space(3))) void lvoid;

__device__ __forceinline__ void gld16(const void* g, void* l) {
  __builtin_amdgcn_global_load_lds((gvoid*)g, (lvoid*)l, 16, 0, 0);
}

// ---------------------------------------------------------------------------
// MFMA f16 GEMM: tile 64x128, BK=64, 4 waves, wave-tile 64x32 (4x2 frags).
// 1-D grid of 512 blocks, bijective XCD swizzle (each XCD gets 8 consecutive
// by => one expert for expert GEMMs). Double-buffered LDS; T4 counted-vmcnt
// pipeline: stage(t+1) -> s_waitcnt vmcnt(6) -> s_barrier -> compute(t) ->
// s_barrier. Loads for t+1 stay in flight across the barriers.
// MODE 0: C[r][col] = v
// MODE 1: A gathered via rowmap (-1 -> zero row TOK), C plain
// MODE 2: C[rowmap[r]][col] = v * gmax[rowmap[r]]  (skip r with rowmap=-1)
// LDS rows are 64 f16 (8 chunks of 16B), XOR-swizzled chunk^=(row&7) via
// pre-swizzled global source (global_load_lds writes linearly).
// ---------------------------------------------------------------------------
template<int MODE>
__global__ __launch_bounds__(256, 2) void gemm_h(
    const f16* __restrict__ A, const f16* __restrict__ Bt,
    const float* __restrict__ bias, f16* __restrict__ C,
    const int* __restrict__ rowmap, const float* __restrict__ gmax,
    int rowsPerExpert, long bStride, int biasStride)
{
  __shared__ f16 As[2][64 * 64];
  __shared__ f16 Bs[2][128 * 64];
  const int tid = threadIdx.x;
  const int w = tid >> 6, l = tid & 63;

  // bijective XCD swizzle: XCD x owns by in [x*8, x*8+8), all bx
  const int orig = blockIdx.x;                 // 0..511
  const int sw = (orig & 7) * 64 + (orig >> 3);
  const int bx = sw & 7, by = sw >> 3;
  const int e = (by * 64) / rowsPerExpert;

  const int lr = l >> 3;                    // row within 8-row staging inst
  const int chunkSw = ((l & 7) ^ lr) * 8;   // pre-swizzled k-chunk (f16 elems)

  // A staging: wave w owns rows w*16 .. w*16+15 (2 insts)
  const f16* pa[2];
  #pragma unroll
  for (int i = 0; i < 2; ++i) {
    int r = by * 64 + w * 16 + i * 8 + lr;
    long tok = r;
    if (MODE == 1) { int t = rowmap[r]; tok = (t < 0) ? (long)TOK : (long)t; }
    pa[i] = A + tok * HID + chunkSw;
  }
  // B staging: wave w owns n-rows w*32 .. w*32+31 (4 insts)
  const f16* pb = Bt + (size_t)e * bStride
                + (size_t)(bx * 128 + w * 32 + lr) * HID + chunkSw;

  f32x4 acc[4][2];
  #pragma unroll
  for (int i = 0; i < 4; ++i)
    #pragma unroll
    for (int j = 0; j < 2; ++j) acc[i][j] = (f32x4){0.f, 0.f, 0.f, 0.f};

  const int g = l >> 4, c = l & 15, sa = c & 7;

  // prologue: stage k=0 into buf 0
  {
    f16* ab = &As[0][(w * 16) * 64];
    f16* bb = &Bs[0][(w * 32) * 64];
    #pragma unroll
    for (int i = 0; i < 2; ++i) gld16(pa[i], ab + i * 8 * 64);
    #pragma unroll
    for (int i = 0; i < 4; ++i) gld16(pb + (size_t)(i * 8) * HID, bb + i * 8 * 64);
  }

  int cur = 0;
  for (int t = 0; t < 15; ++t) {
    {  // stage tile t+1 into buf cur^1 (6 loads stay in flight)
      const int k0 = (t + 1) * 64;
      f16* ab = &As[cur ^ 1][(w * 16) * 64];
      f16* bb = &Bs[cur ^ 1][(w * 32) * 64];
      #pragma unroll
      for (int i = 0; i < 2; ++i) gld16(pa[i] + k0, ab + i * 8 * 64);
      #pragma unroll
      for (int i = 0; i < 4; ++i) gld16(pb + (size_t)(i * 8) * HID + k0, bb + i * 8 * 64);
    }
    asm volatile("s_waitcnt vmcnt(6)" ::: "memory");  // tile t landed
    asm volatile("s_barrier" ::: "memory");           // all waves: buf[cur] full
    __builtin_amdgcn_s_setprio(1);
    #pragma unroll
    for (int h = 0; h < 2; ++h) {
      const int q = ((h * 4 + g) ^ sa) * 8;
      f16x8 af[4], bf[2];
      #pragma unroll
      for (int mi = 0; mi < 4; ++mi)
        af[mi] = *(const f16x8*)&As[cur][(mi * 16 + c) * 64 + q];
      #pragma unroll
      for (int ni = 0; ni < 2; ++ni)
        bf[ni] = *(const f16x8*)&Bs[cur][(w * 32 + ni * 16 + c) * 64 + q];
      #pragma unroll
      for (int mi = 0; mi < 4; ++mi)
        #pragma unroll
        for (int ni = 0; ni < 2; ++ni)
          acc[mi][ni] = __builtin_amdgcn_mfma_f32_16x16x32_f16(
              af[mi], bf[ni], acc[mi][ni], 0, 0, 0);
    }
    __builtin_amdgcn_s_setprio(0);
    asm volatile("s_barrier" ::: "memory");  // buf[cur] free for overwrite
    cur ^= 1;
  }
  // final tile (no prefetch outstanding beyond it)
  asm volatile("s_waitcnt vmcnt(0)" ::: "memory");
  asm volatile("s_barrier" ::: "memory");
  #pragma unroll
  for (int h = 0; h < 2; ++h) {
    const int q = ((h * 4 + g) ^ sa) * 8;
    f16x8 af[4], bf[2];
    #pragma unroll
    for (int mi = 0; mi < 4; ++mi)
      af[mi] = *(const f16x8*)&As[cur][(mi * 16 + c) * 64 + q];
    #pragma unroll
    for (int ni = 0; ni < 2; ++ni)
      bf[ni] = *(const f16x8*)&Bs[cur][(w * 32 + ni * 16 + c) * 64 + q];
    #pragma unroll
    for (int mi = 0; mi < 4; ++mi)
      #pragma unroll
      for (int ni = 0; ni < 2; ++ni)
        acc[mi][ni] = __builtin_amdgcn_mfma_f32_16x16x32_f16(
            af[mi], bf[ni], acc[mi][ni], 0, 0, 0);
  }

  // epilogue: D col = lane&15, row = (lane>>4)*4 + reg
  int tk[4][4];
  float gv[4][4];
  if (MODE == 2) {
    #pragma unroll
    for (int mi = 0; mi < 4; ++mi)
      #pragma unroll
      for (int rr = 0; rr < 4; ++rr) {
        int r = by * 64 + mi * 16 + g * 4 + rr;
        int t = rowmap[r];
        tk[mi][rr] = t;
        gv[mi][rr] = (t >= 0) ? gmax[t] : 0.f;
      }
  }
  #pragma unroll
  for (int ni = 0; ni < 2; ++ni) {
    const int col = bx * 128 + w * 32 + ni * 16 + c;
    const float bv = bias[(size_t)e * biasStride + col];
    #pragma unroll
    for (int mi = 0; mi < 4; ++mi) {
      #pragma unroll
      for (int rr = 0; rr < 4; ++rr) {
        const float v = acc[mi][ni][rr] + bv;
        if (MODE == 2) {
          if (tk[mi][rr] >= 0)
            C[(size_t)tk[mi][rr] * HID + col] = (f16)(v * gv[mi][rr]);
        } else {
          const int row = by * 64 + mi * 16 + g * 4 + rr;
          C[(size_t)row * HID + col] = (f16)v;
        }
      }
    }
  }
}

// ---------------------------------------------------------------------------
// Transpose-cast ALL weights: z in [0,35): 0..2 -> w1,w2,w3; 3..10 -> e1w1;
// 11..18 -> e1w2; 19..26 -> e2w1; 27..34 -> e2w2.  [k][n] f32 -> [n][k] f16.
// 64k x 128n tiles, 8 float4 loads in flight/thread, 2-way-free LDS banks.
// ---------------------------------------------------------------------------
__global__ __launch_bounds__(256) void tcast(
    const float* __restrict__ w1, const float* __restrict__ w2,
    const float* __restrict__ w3,
    const float* __restrict__ g1a, const float* __restrict__ g1b,
    const float* __restrict__ g2a, const float* __restrict__ g2b,
    f16* __restrict__ dst)
{
  __shared__ float t[64][129];
  const int z = blockIdx.z;
  const float* src; int zl = 0;
  if (z == 0) src = w1;
  else if (z == 1) src = w2;
  else if (z == 2) src = w3;
  else if (z < 11) { src = g1a; zl = z - 3; }
  else if (z < 19) { src = g1b; zl = z - 11; }
  else if (z < 27) { src = g2a; zl = z - 19; }
  else             { src = g2b; zl = z - 27; }
  src += (size_t)zl * WSZ;
  f16* d = dst + (size_t)z * WSZ;

  const int tid = threadIdx.x;
  const int kb = blockIdx.y * 64, nb = blockIdx.x * 128;
  const int r = (tid >> 4) & 3, half = tid >> 6, c4 = (tid & 15) * 4;
  // load 8 float4 (all independent -> deep in flight)
  float4 v[8];
  #pragma unroll
  for (int p = 0; p < 8; ++p)
    v[p] = *(const float4*)&src[(size_t)(kb + p * 8 + half * 4 + r) * HID
                                + nb + c4 + (tid & 256 ? 0 : 0)];
  // NOTE: 256 threads: rows covered = p*8 + half*4 + r for half in 0..3? tid>>6 in 0..3
  #pragma unroll
  for (int p = 0; p < 8; ++p) {
    const int row = p * 8 + (tid >> 6) * 2 + (r >> 1);  // unused fallback
  }
  // simpler deterministic mapping: thread covers rows (tid>>4) in 0..15 via two col halves
  __syncthreads();  // (placeholder ordering; real writes below)
  // --- rewrite: direct mapping ---
  // threads: rr = tid>>4 (0..15), cc = tid&15 (cols cc*4 within 64-col half)
  // 8 stores: p in 0..3 selects row-block, hf in 0..1 selects col half.
  {
    const int rr = tid >> 4, cc4 = (tid & 15) * 4;
    #pragma unroll
    for (int p = 0; p < 4; ++p) {
      #pragma unroll
      for (int hf = 0; hf < 2; ++hf) {
        float4 vv = *(const float4*)&src[(size_t)(kb + p * 16 + rr) * HID
                                         + nb + hf * 64 + cc4];
        t[p * 16 + rr][hf * 64 + cc4 + 0] = vv.x;
        t[p * 16 + rr][hf * 64 + cc4 + 1] = vv.y;
        t[p * 16 + rr][hf * 64 + cc4 + 2] = vv.z;
        t[p * 16 + rr][hf * 64 + cc4 + 3] = vv.w;
      }
    }
  }
  __syncthreads();
  #pragma unroll
  for (int it = 0; it < 4; ++it) {
    const int p = it * 256 + tid;
    const int n = p >> 3, kc = p & 7;
    f16x8 o;
    #pragma unroll
    for (int j = 0; j < 8; ++j) o[j] = (f16)t[kc * 8 + j][n];
    *(f16x8*)&d[(size_t)(nb + n) * HID + kb + kc * 8] = o;
  }
}

// ---------------------------------------------------------------------------
// prep: castx (x f32 -> X0 f16) + zero C1/C2 + zero the two gather pad rows
__global__ void prep(const float* __restrict__ x, f16* __restrict__ X0,
                     f16* __restrict__ c1, f16* __restrict__ c2,
                     f16* __restrict__ p1, f16* __restrict__ p2) {
  const size_t i = (size_t)blockIdx.x * 256 + threadIdx.x;  // 1048576 threads
  float4 v = *(const float4*)&x[i * 4];
  f16x4 o = {(f16)v.x, (f16)v.y, (f16)v.z, (f16)v.w};
  *(f16x4*)&X0[i * 4] = o;
  const f16x8 zz = {0, 0, 0, 0, 0, 0, 0, 0};
  if (i < 524288) { ((f16x8*)c1)[i] = zz; ((f16x8*)c2)[i] = zz; }
  if (i < 128)    { ((f16x8*)p1)[i] = zz; ((f16x8*)p2)[i] = zz; }
}

// ---------------------------------------------------------------------------
// Gating from f16 activations: 8 tokens/block, 32 lanes/token, f32 accum.
// ---------------------------------------------------------------------------
__global__ __launch_bounds__(256) void gate_kernel(
    const f16* __restrict__ act, const float* __restrict__ wg,
    int* __restrict__ idx, float* __restrict__ gmax)
{
  const int tid = threadIdx.x;
  const int tok = blockIdx.x * 8 + (tid >> 5);
  const int sl = tid & 31;
  const f16* row = act + (size_t)tok * HID + sl * 32;
  float xv[32];
  #pragma unroll
  for (int v = 0; v < 4; ++v) {
    f16x8 hv = *(const f16x8*)(row + v * 8);
    #pragma unroll
    for (int j = 0; j < 8; ++j) xv[v * 8 + j] = (float)hv[j];
  }
  float p[NEXP];
  #pragma unroll
  for (int e = 0; e < NEXP; ++e) p[e] = 0.f;
  const float* wr_ = wg + (size_t)(sl * 32) * NEXP;
  #pragma unroll
  for (int j = 0; j < 32; ++j) {
    #pragma unroll
    for (int e = 0; e < NEXP; ++e) p[e] += xv[j] * wr_[j * NEXP + e];
  }
  #pragma unroll
  for (int m = 1; m < 32; m <<= 1) {
    #pragma unroll
    for (int e = 0; e < NEXP; ++e) p[e] += __shfl_xor(p[e], m, 64);
  }
  if (sl == 0) {
    float mx = p[0]; int am = 0;
    #pragma unroll
    for (int e = 1; e < NEXP; ++e)
      if (p[e] > mx) { mx = p[e]; am = e; }
    float s = 0.f;
    #pragma unroll
    for (int e = 0; e < NEXP; ++e) s += expf(p[e] - mx);
    idx[tok] = am;
    gmax[tok] = 1.f / s;
  }
}

// ---------------------------------------------------------------------------
// Capacity scan (cumsum-of-one_hot semantics): wave e owns expert e.
// ---------------------------------------------------------------------------
__global__ __launch_bounds__(512) void scan_kernel(
    const int* __restrict__ idx, int* __restrict__ rowmap)
{
  __shared__ int sidx[TOK];
  const int tid = threadIdx.x;
  for (int i = tid; i < TOK; i += 512) sidx[i] = idx[i];
  for (int i = tid; i < NEXP * CAP; i += 512) rowmap[i] = -1;
  __syncthreads();
  const int wave = tid >> 6, lane = tid & 63;
  int running = 0;
  for (int ch = 0; ch < TOK / 64; ++ch) {
    int t = ch * 64 + lane;
    bool flag = (sidx[t] == wave);
    unsigned long long m = __ballot(flag);
    int pos = running + __popcll(m & ((1ull << lane) - 1ull));
    if (flag && pos < CAP) rowmap[wave * CAP + pos] = t;
    running += __popcll(m);
  }
}

// ---------------------------------------------------------------------------
// sent[b][h] = mean_s (a + c), f16 inputs, f32 accum.  grid (2,8), 256 thr.
// ---------------------------------------------------------------------------
__global__ __launch_bounds__(256) void mean_kernel(
    const f16* __restrict__ a, const f16* __restrict__ c,
    float* __restrict__ sent)
{
  const int h2 = blockIdx.x * 256 + threadIdx.x;  // f16x2 column, 0..511
  const int b = blockIdx.y;
  const f16x2* pa = (const f16x2*)(a + (size_t)b * 512 * HID) + h2;
  const f16x2* pc = (const f16x2*)(c + (size_t)b * 512 * HID) + h2;
  float a0 = 0.f, a1 = 0.f;
  for (int s = 0; s < 512; ++s) {
    f16x2 va = pa[(size_t)s * 512];
    f16x2 vc = pc[(size_t)s * 512];
    a0 += (float)va[0] + (float)vc[0];
    a1 += (float)va[1] + (float)vc[1];
  }
  sent[b * HID + h2 * 2]     = a0 * (1.f / 512.f);
  sent[b * HID + h2 * 2 + 1] = a1 * (1.f / 512.f);
}

__global__ __launch_bounds__(1024) void loss_kernel(
    const float* __restrict__ sent, const int* __restrict__ y,
    float* __restrict__ out)
{
  __shared__ float red[1024];
  float loss = 0.0f;
  for (int b = 0; b < 8; ++b) {
    float v = sent[b * HID + threadIdx.x];
    red[threadIdx.x] = v;
    __syncthreads();
    for (int s = 512; s > 0; s >>= 1) {
      if (threadIdx.x < s)
        red[threadIdx.x] = fmaxf(red[threadIdx.x], red[threadIdx.x + s]);
      __syncthreads();
    }
    float m = red[0];
    __syncthreads();
    red[threadIdx.x] = expf(v - m);
    __syncthreads();
    for (int s = 512; s > 0; s >>= 1) {
      if (threadIdx.x < s) red[threadIdx.x] += red[threadIdx.x + s];
      __syncthreads();
    }
    if (threadIdx.x == 0) {
      float lse = m + logf(red[0]);
      loss += -(sent[b * HID + y[b]] - lse);
    }
    __syncthreads();
  }
  if (threadIdx.x == 0) out[0] = loss * (1.0f / 8.0f);
}

// ---------------------------------------------------------------------------
extern "C" void kernel_launch(void* const* d_in, const int* in_sizes, int n_in,
                              void* d_out, int out_size, void* d_ws, size_t ws_size,
                              hipStream_t stream)
{
  const float* x    = (const float*)d_in[0];
  const int*   y    = (const int*)d_in[1];
  const float* w1   = (const float*)d_in[2];
  const float* b1   = (const float*)d_in[3];
  const float* w2   = (const float*)d_in[4];
  const float* b2   = (const float*)d_in[5];
  const float* w3   = (const float*)d_in[6];
  const float* b3   = (const float*)d_in[7];
  const float* wg1  = (const float*)d_in[8];
  const float* e1w1 = (const float*)d_in[9];
  const float* e1b1 = (const float*)d_in[10];
  const float* e1w2 = (const float*)d_in[11];
  const float* e1b2 = (const float*)d_in[12];
  const float* wg2  = (const float*)d_in[13];
  const float* e2w1 = (const float*)d_in[14];
  const float* e2b1 = (const float*)d_in[15];
  const float* e2w2 = (const float*)d_in[16];
  const float* e2b2 = (const float*)d_in[17];

  // workspace (~134 MB)
  f16* WT = (f16*)d_ws;                          // 35 x [1024][1024] f16
  f16* X0 = WT + (size_t)35 * WSZ;               // [4096][1024]
  f16* H  = X0 + (size_t)TOK * HID;              // [4097][1024] (pad row)
  f16* EA = H + (size_t)(TOK + 1) * HID;         // [4096][1024] expert hidden
  f16* C1 = EA + (size_t)TOK * HID;              // [4096][1024] combine1 out
  f16* M1 = C1 + (size_t)TOK * HID;              // [4097][1024] (pad row)
  f16* C2 = M1 + (size_t)(TOK + 1) * HID;        // [4096][1024] combine2 out
  f16* O  = C2 + (size_t)TOK * HID;              // [4096][1024] final proj
  float* gmax  = (float*)(O + (size_t)TOK * HID);
  int* idx     = (int*)(gmax + TOK);
  int* rowmap  = idx + TOK;
  float* sent  = (float*)(rowmap + TOK);

  prep<<<4096, 256, 0, stream>>>(x, X0, C1, C2,
                                 H + (size_t)TOK * HID, M1 + (size_t)TOK * HID);
  tcast<<<dim3(8, 16, 35), 256, 0, stream>>>(w1, w2, w3, e1w1, e1w2, e2w1, e2w2, WT);

  // hidden = x @ w1 + b1
  gemm_h<0><<<512, 256, 0, stream>>>(X0, WT, b1, H, nullptr, nullptr, TOK, 0, 0);

  // ---- MoE layer 1 ----
  gate_kernel<<<512, 256, 0, stream>>>(H, wg1, idx, gmax);
  scan_kernel<<<1, 512, 0, stream>>>(idx, rowmap);
  gemm_h<1><<<512, 256, 0, stream>>>(H,  WT + (size_t)3 * WSZ,  e1b1, EA, rowmap, nullptr, CAP, WSZ, HID);
  gemm_h<2><<<512, 256, 0, stream>>>(EA, WT + (size_t)11 * WSZ, e1b2, C1, rowmap, gmax,    CAP, WSZ, HID);

  // out = moe1 @ w2 + b2
  gemm_h<0><<<512, 256, 0, stream>>>(C1, WT + (size_t)1 * WSZ, b2, M1, nullptr, nullptr, TOK, 0, 0);

  // ---- MoE layer 2 ----
  gate_kernel<<<512, 256, 0, stream>>>(M1, wg2, idx, gmax);
  scan_kernel<<<1, 512, 0, stream>>>(idx, rowmap);
  gemm_h<1><<<512, 256, 0, stream>>>(M1, WT + (size_t)19 * WSZ, e2b1, EA, rowmap, nullptr, CAP, WSZ, HID);
  gemm_h<2><<<512, 256, 0, stream>>>(EA, WT + (size_t)27 * WSZ, e2b2, C2, rowmap, gmax,    CAP, WSZ, HID);

  // out = moe2 @ w3 + b3
  gemm_h<0><<<512, 256, 0, stream>>>(C2, WT + (size_t)2 * WSZ, b3, O, nullptr, nullptr, TOK, 0, 0);

  // final reduction
  mean_kernel<<<dim3(2, 8), 256, 0, stream>>>(H, O, sent);
  loss_kernel<<<1, 1024, 0, stream>>>(sent, y, (float*)d_out);
}

// Round 6
// 228.973 us; speedup vs baseline: 1.3952x; 1.1487x over previous
//
#include <hip/hip_runtime.h>

#define TOK 4096
#define HID 1024
#define NEXP 8
#define CAP 512
#define WSZ 1048576  // HID*HID

typedef _Float16 f16;
typedef f16 f16x8 __attribute__((ext_vector_type(8)));
typedef f16 f16x4 __attribute__((ext_vector_type(4)));
typedef f16 f16x2 __attribute__((ext_vector_type(2)));
typedef float f32x4 __attribute__((ext_vector_type(4)));

typedef const __attribute__((address_space(1))) void gvoid;
typedef __attribute__((address_space(3))) void lvoid;

__device__ __forceinline__ void gld16(const void* g, void* l) {
  __builtin_amdgcn_global_load_lds((gvoid*)g, (lvoid*)l, 16, 0, 0);
}

// ---------------------------------------------------------------------------
// MFMA f16 GEMM: tile 128x128, BK=64, 512 thr = 8 waves (2 row x 4 col),
// wave-tile 64x32 (4x2 frags of 16x16x32). Grid 256 blocks, bijective XCD
// swizzle: XCD x owns by in [4x, 4x+4) (= exactly one expert for expert
// GEMMs -> its 2MB B panel is L2-resident).
// Staging: waves 0-3 stage A rows [w*32,w*32+32), waves 4-7 stage B rows;
// 4 global_load_lds insts per wave per K-step. T4 counted-vmcnt 2-phase:
// stage(t+1) -> s_waitcnt vmcnt(4) (tile t landed) -> barrier -> MFMA ->
// barrier. Tile t+1's loads stay in flight across both barriers.
// MODE 0: C[r][col] = v
// MODE 1: A gathered via rowmap (-1 -> zero row TOK), C plain
// MODE 2: C[rowmap[r]][col] = v * gmax[rowmap[r]]  (skip r with rowmap=-1)
// LDS rows 64 f16 (8 chunks of 16B) XOR-swizzled chunk^=(row&7) via
// pre-swizzled global source (global_load_lds writes linearly).
// ---------------------------------------------------------------------------
template<int MODE>
__global__ __launch_bounds__(512, 1) void gemm_h(
    const f16* __restrict__ A, const f16* __restrict__ Bt,
    const float* __restrict__ bias, f16* __restrict__ C,
    const int* __restrict__ rowmap, const float* __restrict__ gmax,
    int rowsPerExpert, long bStride, int biasStride)
{
  __shared__ f16 As[2][128 * 64];
  __shared__ f16 Bs[2][128 * 64];
  const int tid = threadIdx.x;
  const int w = tid >> 6, l = tid & 63;
  const int wr = w >> 2, wc = w & 3;

  // bijective XCD swizzle: XCD x owns by in [4x, 4x+4), all bx
  const int orig = blockIdx.x;                 // 0..255
  const int sw = (orig & 7) * 32 + (orig >> 3);
  const int bx = sw & 7, by = sw >> 3;
  const int e = (by * 128) / rowsPerExpert;

  const int lr = l >> 3;                    // row within 8-row staging inst
  const int chunkSw = ((l & 7) ^ lr) * 8;   // pre-swizzled k-chunk (f16 elems)

  // staging sources: waves 0-3 -> A rows w*32.., waves 4-7 -> B rows (w-4)*32..
  const f16* pst[4];
  if (w < 4) {
    #pragma unroll
    for (int i = 0; i < 4; ++i) {
      int r = by * 128 + w * 32 + i * 8 + lr;
      long tok = r;
      if (MODE == 1) { int t = rowmap[r]; tok = (t < 0) ? (long)TOK : (long)t; }
      pst[i] = A + tok * HID + chunkSw;
    }
  } else {
    #pragma unroll
    for (int i = 0; i < 4; ++i)
      pst[i] = Bt + (size_t)e * bStride
             + (size_t)(bx * 128 + (w - 4) * 32 + i * 8 + lr) * HID + chunkSw;
  }

  f32x4 acc[4][2];
  #pragma unroll
  for (int i = 0; i < 4; ++i)
    #pragma unroll
    for (int j = 0; j < 2; ++j) acc[i][j] = (f32x4){0.f, 0.f, 0.f, 0.f};

  const int g = l >> 4, c = l & 15, sa = c & 7;

  // prologue: stage k=0 into buf 0
  {
    f16* db = (w < 4) ? &As[0][(w * 32) * 64] : &Bs[0][((w - 4) * 32) * 64];
    #pragma unroll
    for (int i = 0; i < 4; ++i) gld16(pst[i], db + i * 8 * 64);
  }

  int cur = 0;
  for (int t = 0; t < 15; ++t) {
    {  // stage tile t+1 into buf cur^1 (4 loads/wave stay in flight)
      const int k0 = (t + 1) * 64;
      f16* db = (w < 4) ? &As[cur ^ 1][(w * 32) * 64]
                        : &Bs[cur ^ 1][((w - 4) * 32) * 64];
      #pragma unroll
      for (int i = 0; i < 4; ++i) gld16(pst[i] + k0, db + i * 8 * 64);
    }
    asm volatile("s_waitcnt vmcnt(4)" ::: "memory");  // tile t landed
    asm volatile("s_barrier" ::: "memory");           // buf[cur] full for all
    __builtin_amdgcn_s_setprio(1);
    #pragma unroll
    for (int h = 0; h < 2; ++h) {
      const int q = ((h * 4 + g) ^ sa) * 8;
      f16x8 af[4], bf[2];
      #pragma unroll
      for (int mi = 0; mi < 4; ++mi)
        af[mi] = *(const f16x8*)&As[cur][(wr * 64 + mi * 16 + c) * 64 + q];
      #pragma unroll
      for (int ni = 0; ni < 2; ++ni)
        bf[ni] = *(const f16x8*)&Bs[cur][(wc * 32 + ni * 16 + c) * 64 + q];
      #pragma unroll
      for (int mi = 0; mi < 4; ++mi)
        #pragma unroll
        for (int ni = 0; ni < 2; ++ni)
          acc[mi][ni] = __builtin_amdgcn_mfma_f32_16x16x32_f16(
              af[mi], bf[ni], acc[mi][ni], 0, 0, 0);
    }
    __builtin_amdgcn_s_setprio(0);
    asm volatile("s_barrier" ::: "memory");  // buf[cur] free for overwrite
    cur ^= 1;
  }
  // final tile
  asm volatile("s_waitcnt vmcnt(0)" ::: "memory");
  asm volatile("s_barrier" ::: "memory");
  #pragma unroll
  for (int h = 0; h < 2; ++h) {
    const int q = ((h * 4 + g) ^ sa) * 8;
    f16x8 af[4], bf[2];
    #pragma unroll
    for (int mi = 0; mi < 4; ++mi)
      af[mi] = *(const f16x8*)&As[cur][(wr * 64 + mi * 16 + c) * 64 + q];
    #pragma unroll
    for (int ni = 0; ni < 2; ++ni)
      bf[ni] = *(const f16x8*)&Bs[cur][(wc * 32 + ni * 16 + c) * 64 + q];
    #pragma unroll
    for (int mi = 0; mi < 4; ++mi)
      #pragma unroll
      for (int ni = 0; ni < 2; ++ni)
        acc[mi][ni] = __builtin_amdgcn_mfma_f32_16x16x32_f16(
            af[mi], bf[ni], acc[mi][ni], 0, 0, 0);
  }

  // epilogue: D col = lane&15, row = (lane>>4)*4 + reg
  int tk[4][4];
  float gv[4][4];
  if (MODE == 2) {
    #pragma unroll
    for (int mi = 0; mi < 4; ++mi)
      #pragma unroll
      for (int rr = 0; rr < 4; ++rr) {
        int r = by * 128 + wr * 64 + mi * 16 + g * 4 + rr;
        int t = rowmap[r];
        tk[mi][rr] = t;
        gv[mi][rr] = (t >= 0) ? gmax[t] : 0.f;
      }
  }
  #pragma unroll
  for (int ni = 0; ni < 2; ++ni) {
    const int col = bx * 128 + wc * 32 + ni * 16 + c;
    const float bv = bias[(size_t)e * biasStride + col];
    #pragma unroll
    for (int mi = 0; mi < 4; ++mi) {
      #pragma unroll
      for (int rr = 0; rr < 4; ++rr) {
        const float v = acc[mi][ni][rr] + bv;
        if (MODE == 2) {
          if (tk[mi][rr] >= 0)
            C[(size_t)tk[mi][rr] * HID + col] = (f16)(v * gv[mi][rr]);
        } else {
          const int row = by * 128 + wr * 64 + mi * 16 + g * 4 + rr;
          C[(size_t)row * HID + col] = (f16)v;
        }
      }
    }
  }
}

// ---------------------------------------------------------------------------
// Transpose-cast ALL weights: z in [0,35): 0..2 -> w1,w2,w3; 3..10 -> e1w1;
// 11..18 -> e1w2; 19..26 -> e2w1; 27..34 -> e2w2.  [k][n] f32 -> [n][k] f16.
// 64x64 tiles, f32 LDS [64][65] (16.9 KB) -> 8 blocks/CU; both LDS phases
// 2-way bank aliasing (free). 4 float4 loads in flight per thread.
// ---------------------------------------------------------------------------
__global__ __launch_bounds__(256, 8) void tcast(
    const float* __restrict__ w1, const float* __restrict__ w2,
    const float* __restrict__ w3,
    const float* __restrict__ g1a, const float* __restrict__ g1b,
    const float* __restrict__ g2a, const float* __restrict__ g2b,
    f16* __restrict__ dst)
{
  __shared__ float t[64][65];
  const int z = blockIdx.z;
  const float* src; int zl = 0;
  if (z == 0) src = w1;
  else if (z == 1) src = w2;
  else if (z == 2) src = w3;
  else if (z < 11) { src = g1a; zl = z - 3; }
  else if (z < 19) { src = g1b; zl = z - 11; }
  else if (z < 27) { src = g2a; zl = z - 19; }
  else             { src = g2b; zl = z - 27; }
  src += (size_t)zl * WSZ;
  f16* d = dst + (size_t)z * WSZ;

  const int tid = threadIdx.x;
  const int kb = blockIdx.y * 64, nb = blockIdx.x * 64;
  const int rr = tid >> 4, c4 = (tid & 15) * 4;
  float4 v[4];
  #pragma unroll
  for (int p = 0; p < 4; ++p)
    v[p] = *(const float4*)&src[(size_t)(kb + p * 16 + rr) * HID + nb + c4];
  #pragma unroll
  for (int p = 0; p < 4; ++p) {
    t[p * 16 + rr][c4 + 0] = v[p].x;
    t[p * 16 + rr][c4 + 1] = v[p].y;
    t[p * 16 + rr][c4 + 2] = v[p].z;
    t[p * 16 + rr][c4 + 3] = v[p].w;
  }
  __syncthreads();
  #pragma unroll
  for (int half = 0; half < 2; ++half) {
    const int p = half * 256 + tid;
    const int n = p >> 3, kc = p & 7;
    f16x8 o;
    #pragma unroll
    for (int j = 0; j < 8; ++j) o[j] = (f16)t[kc * 8 + j][n];
    *(f16x8*)&d[(size_t)(nb + n) * HID + kb + kc * 8] = o;
  }
}

// ---------------------------------------------------------------------------
// prep: castx (x f32 -> X0 f16) + zero C1/C2 + zero the two gather pad rows
__global__ void prep(const float* __restrict__ x, f16* __restrict__ X0,
                     f16* __restrict__ c1, f16* __restrict__ c2,
                     f16* __restrict__ p1, f16* __restrict__ p2) {
  const size_t i = (size_t)blockIdx.x * 256 + threadIdx.x;  // 1048576 threads
  float4 v = *(const float4*)&x[i * 4];
  f16x4 o = {(f16)v.x, (f16)v.y, (f16)v.z, (f16)v.w};
  *(f16x4*)&X0[i * 4] = o;
  const f16x8 zz = {0, 0, 0, 0, 0, 0, 0, 0};
  if (i < 524288) { ((f16x8*)c1)[i] = zz; ((f16x8*)c2)[i] = zz; }
  if (i < 128)    { ((f16x8*)p1)[i] = zz; ((f16x8*)p2)[i] = zz; }
}

// ---------------------------------------------------------------------------
// Gating from f16 activations: 8 tokens/block, 32 lanes/token, f32 accum.
// ---------------------------------------------------------------------------
__global__ __launch_bounds__(256) void gate_kernel(
    const f16* __restrict__ act, const float* __restrict__ wg,
    int* __restrict__ idx, float* __restrict__ gmax)
{
  const int tid = threadIdx.x;
  const int tok = blockIdx.x * 8 + (tid >> 5);
  const int sl = tid & 31;
  const f16* row = act + (size_t)tok * HID + sl * 32;
  float xv[32];
  #pragma unroll
  for (int v = 0; v < 4; ++v) {
    f16x8 hv = *(const f16x8*)(row + v * 8);
    #pragma unroll
    for (int j = 0; j < 8; ++j) xv[v * 8 + j] = (float)hv[j];
  }
  float p[NEXP];
  #pragma unroll
  for (int e = 0; e < NEXP; ++e) p[e] = 0.f;
  const float* wr_ = wg + (size_t)(sl * 32) * NEXP;
  #pragma unroll
  for (int j = 0; j < 32; ++j) {
    #pragma unroll
    for (int e = 0; e < NEXP; ++e) p[e] += xv[j] * wr_[j * NEXP + e];
  }
  #pragma unroll
  for (int m = 1; m < 32; m <<= 1) {
    #pragma unroll
    for (int e = 0; e < NEXP; ++e) p[e] += __shfl_xor(p[e], m, 64);
  }
  if (sl == 0) {
    float mx = p[0]; int am = 0;
    #pragma unroll
    for (int e = 1; e < NEXP; ++e)
      if (p[e] > mx) { mx = p[e]; am = e; }
    float s = 0.f;
    #pragma unroll
    for (int e = 0; e < NEXP; ++e) s += expf(p[e] - mx);
    idx[tok] = am;
    gmax[tok] = 1.f / s;
  }
}

// ---------------------------------------------------------------------------
// Capacity scan (cumsum-of-one_hot semantics): wave e owns expert e.
// ---------------------------------------------------------------------------
__global__ __launch_bounds__(512) void scan_kernel(
    const int* __restrict__ idx, int* __restrict__ rowmap)
{
  __shared__ int sidx[TOK];
  const int tid = threadIdx.x;
  for (int i = tid; i < TOK; i += 512) sidx[i] = idx[i];
  for (int i = tid; i < NEXP * CAP; i += 512) rowmap[i] = -1;
  __syncthreads();
  const int wave = tid >> 6, lane = tid & 63;
  int running = 0;
  for (int ch = 0; ch < TOK / 64; ++ch) {
    int t = ch * 64 + lane;
    bool flag = (sidx[t] == wave);
    unsigned long long m = __ballot(flag);
    int pos = running + __popcll(m & ((1ull << lane) - 1ull));
    if (flag && pos < CAP) rowmap[wave * CAP + pos] = t;
    running += __popcll(m);
  }
}

// ---------------------------------------------------------------------------
// mean stage 1: partial[sc][b][h] = sum over 32 s of (a+c).  grid (2,8,16).
// ---------------------------------------------------------------------------
__global__ __launch_bounds__(256) void mean1_kernel(
    const f16* __restrict__ a, const f16* __restrict__ c,
    float* __restrict__ partial)
{
  const int h2 = blockIdx.x * 256 + threadIdx.x;  // 0..511
  const int b = blockIdx.y, sc = blockIdx.z;
  const f16x2* pa = (const f16x2*)(a + ((size_t)b * 512 + sc * 32) * HID) + h2;
  const f16x2* pc = (const f16x2*)(c + ((size_t)b * 512 + sc * 32) * HID) + h2;
  float a0 = 0.f, a1 = 0.f;
  #pragma unroll 4
  for (int s = 0; s < 32; ++s) {
    f16x2 va = pa[(size_t)s * 512];
    f16x2 vc = pc[(size_t)s * 512];
    a0 += (float)va[0] + (float)vc[0];
    a1 += (float)va[1] + (float)vc[1];
  }
  float* o = partial + ((size_t)sc * 8 + b) * HID;
  o[h2 * 2]     = a0;
  o[h2 * 2 + 1] = a1;
}

// mean stage 2: sent[b][h] = (1/512) sum over 16 sc.  grid (2,8).
__global__ __launch_bounds__(256) void mean2_kernel(
    const float* __restrict__ partial, float* __restrict__ sent)
{
  const int h2 = blockIdx.x * 256 + threadIdx.x;
  const int b = blockIdx.y;
  float a0 = 0.f, a1 = 0.f;
  #pragma unroll
  for (int sc = 0; sc < 16; ++sc) {
    const float* p = partial + ((size_t)sc * 8 + b) * HID + h2 * 2;
    a0 += p[0]; a1 += p[1];
  }
  sent[b * HID + h2 * 2]     = a0 * (1.f / 512.f);
  sent[b * HID + h2 * 2 + 1] = a1 * (1.f / 512.f);
}

__global__ __launch_bounds__(1024) void loss_kernel(
    const float* __restrict__ sent, const int* __restrict__ y,
    float* __restrict__ out)
{
  __shared__ float red[1024];
  float loss = 0.0f;
  for (int b = 0; b < 8; ++b) {
    float v = sent[b * HID + threadIdx.x];
    red[threadIdx.x] = v;
    __syncthreads();
    for (int s = 512; s > 0; s >>= 1) {
      if (threadIdx.x < s)
        red[threadIdx.x] = fmaxf(red[threadIdx.x], red[threadIdx.x + s]);
      __syncthreads();
    }
    float m = red[0];
    __syncthreads();
    red[threadIdx.x] = expf(v - m);
    __syncthreads();
    for (int s = 512; s > 0; s >>= 1) {
      if (threadIdx.x < s) red[threadIdx.x] += red[threadIdx.x + s];
      __syncthreads();
    }
    if (threadIdx.x == 0) {
      float lse = m + logf(red[0]);
      loss += -(sent[b * HID + y[b]] - lse);
    }
    __syncthreads();
  }
  if (threadIdx.x == 0) out[0] = loss * (1.0f / 8.0f);
}

// ---------------------------------------------------------------------------
extern "C" void kernel_launch(void* const* d_in, const int* in_sizes, int n_in,
                              void* d_out, int out_size, void* d_ws, size_t ws_size,
                              hipStream_t stream)
{
  const float* x    = (const float*)d_in[0];
  const int*   y    = (const int*)d_in[1];
  const float* w1   = (const float*)d_in[2];
  const float* b1   = (const float*)d_in[3];
  const float* w2   = (const float*)d_in[4];
  const float* b2   = (const float*)d_in[5];
  const float* w3   = (const float*)d_in[6];
  const float* b3   = (const float*)d_in[7];
  const float* wg1  = (const float*)d_in[8];
  const float* e1w1 = (const float*)d_in[9];
  const float* e1b1 = (const float*)d_in[10];
  const float* e1w2 = (const float*)d_in[11];
  const float* e1b2 = (const float*)d_in[12];
  const float* wg2  = (const float*)d_in[13];
  const float* e2w1 = (const float*)d_in[14];
  const float* e2b1 = (const float*)d_in[15];
  const float* e2w2 = (const float*)d_in[16];
  const float* e2b2 = (const float*)d_in[17];

  // workspace (~135 MB)
  f16* WT = (f16*)d_ws;                          // 35 x [1024][1024] f16
  f16* X0 = WT + (size_t)35 * WSZ;               // [4096][1024]
  f16* H  = X0 + (size_t)TOK * HID;              // [4097][1024] (pad row)
  f16* EA = H + (size_t)(TOK + 1) * HID;         // [4096][1024] expert hidden
  f16* C1 = EA + (size_t)TOK * HID;              // [4096][1024] combine1 out
  f16* M1 = C1 + (size_t)TOK * HID;              // [4097][1024] (pad row)
  f16* C2 = M1 + (size_t)(TOK + 1) * HID;        // [4096][1024] combine2 out
  f16* O  = C2 + (size_t)TOK * HID;              // [4096][1024] final proj
  float* gmax  = (float*)(O + (size_t)TOK * HID);
  int* idx     = (int*)(gmax + TOK);
  int* rowmap  = idx + TOK;
  float* sent  = (float*)(rowmap + TOK);
  float* partial = sent + 8 * HID;               // [16][8][1024] f32

  prep<<<4096, 256, 0, stream>>>(x, X0, C1, C2,
                                 H + (size_t)TOK * HID, M1 + (size_t)TOK * HID);
  tcast<<<dim3(16, 16, 35), 256, 0, stream>>>(w1, w2, w3, e1w1, e1w2, e2w1, e2w2, WT);

  // hidden = x @ w1 + b1
  gemm_h<0><<<256, 512, 0, stream>>>(X0, WT, b1, H, nullptr, nullptr, TOK, 0, 0);

  // ---- MoE layer 1 ----
  gate_kernel<<<512, 256, 0, stream>>>(H, wg1, idx, gmax);
  scan_kernel<<<1, 512, 0, stream>>>(idx, rowmap);
  gemm_h<1><<<256, 512, 0, stream>>>(H,  WT + (size_t)3 * WSZ,  e1b1, EA, rowmap, nullptr, CAP, WSZ, HID);
  gemm_h<2><<<256, 512, 0, stream>>>(EA, WT + (size_t)11 * WSZ, e1b2, C1, rowmap, gmax,    CAP, WSZ, HID);

  // out = moe1 @ w2 + b2
  gemm_h<0><<<256, 512, 0, stream>>>(C1, WT + (size_t)1 * WSZ, b2, M1, nullptr, nullptr, TOK, 0, 0);

  // ---- MoE layer 2 ----
  gate_kernel<<<512, 256, 0, stream>>>(M1, wg2, idx, gmax);
  scan_kernel<<<1, 512, 0, stream>>>(idx, rowmap);
  gemm_h<1><<<256, 512, 0, stream>>>(M1, WT + (size_t)19 * WSZ, e2b1, EA, rowmap, nullptr, CAP, WSZ, HID);
  gemm_h<2><<<256, 512, 0, stream>>>(EA, WT + (size_t)27 * WSZ, e2b2, C2, rowmap, gmax,    CAP, WSZ, HID);

  // out = moe2 @ w3 + b3
  gemm_h<0><<<256, 512, 0, stream>>>(C2, WT + (size_t)2 * WSZ, b3, O, nullptr, nullptr, TOK, 0, 0);

  // final reduction
  mean1_kernel<<<dim3(2, 8, 16), 256, 0, stream>>>(H, O, partial);
  mean2_kernel<<<dim3(2, 8), 256, 0, stream>>>(partial, sent);
  loss_kernel<<<1, 1024, 0, stream>>>(sent, y, (float*)d_out);
}